// Round 6
// baseline (91.653 us; speedup 1.0000x reference)
//
#include <hip/hip_runtime.h>
#include <hip/hip_bf16.h>
#include <cstdint>

#define NDIM 128
#define KCLAMP 10.0f

using bf16x8 = __attribute__((ext_vector_type(8))) short;
using f32x4  = __attribute__((ext_vector_type(4))) float;
using f32x2  = __attribute__((ext_vector_type(2))) float;

__device__ __forceinline__ uint16_t f2bf(float f) {
    uint32_t u = __float_as_uint(f);
    uint32_t r = (u + 0x7fffu + ((u >> 16) & 1u)) >> 16;   // RNE
    return (uint16_t)r;
}
__device__ __forceinline__ float bf_lo(uint32_t v) { return __uint_as_float(v << 16); }
__device__ __forceinline__ float bf_hi(uint32_t v) { return __uint_as_float(v & 0xffff0000u); }

// ---------------- k1: trans = bf16((h * norm_src) @ W)  +  rowptr ----------------
// GEMM blocks: 256 thr (4 waves), 64 rows each. LDS: A-tile 16KB (swizzled) +
// W-frag 32KB (built from global W, L2-hot). rowptr blocks follow in same grid.
__global__ __launch_bounds__(256) void k1_trans_rowptr(
        const float* __restrict__ h, const int* __restrict__ odeg,
        const float* __restrict__ W, uint16_t* __restrict__ trans, int M,
        const int* __restrict__ sdst, int E, int* __restrict__ row_start, int ndst,
        int gemmBlocks) {
    int b = blockIdx.x;
    int tx = threadIdx.x;

    if (b >= gemmBlocks) {                 // ---- rowptr role ----
        int d = (b - gemmBlocks) * 256 + tx;
        if (d > ndst) return;
        int lo = 0, hi = E;
        while (lo < hi) {
            int mid = (lo + hi) >> 1;
            if (sdst[mid] < d) lo = mid + 1; else hi = mid;
        }
        row_start[d] = lo;
        return;
    }

    // ---- GEMM role ----
    __shared__ uint16_t Ws[NDIM * NDIM];     // 32 KB, B-frag layout
    __shared__ uint16_t Asm[64 * NDIM];      // 16 KB, swizzled bf16 A-tile

    int r0 = b * 64;

    // stage A: 64 rows x 128 cols, coalesced f32, scale by norm_src, bf16, swizzle
    for (int i = tx; i < 64 * (NDIM / 4); i += 256) {
        int row_loc = i >> 5;                // 32 float4 per row
        int col4    = i & 31;
        int row = r0 + row_loc;
        float4 v = {0.f, 0.f, 0.f, 0.f};
        float nrm = 0.f;
        if (row < M) {
            v = ((const float4*)h)[(size_t)row * (NDIM / 4) + col4];
            nrm = rsqrtf(fmaxf((float)odeg[row], 1.0f));
        }
        ushort4 o;
        o.x = f2bf(v.x * nrm);
        o.y = f2bf(v.y * nrm);
        o.z = f2bf(v.z * nrm);
        o.w = f2bf(v.w * nrm);
        int byte = (row_loc * 256 + col4 * 8) ^ ((row_loc & 7) << 4);
        *(ushort4*)((char*)Asm + byte) = o;
    }

    // stage W fragments: Ws[t] = bf16(W[k][col]),
    // t=((n*4+s)*64+lane)*8+i, k=s*32+8*(lane>>4)+i, col=n*16+(lane&15)
    for (int t = tx; t < NDIM * NDIM; t += 256) {
        int i    = t & 7;
        int ln   = (t >> 3) & 63;
        int s    = (t >> 9) & 3;
        int n    = t >> 11;
        int k    = s * 32 + 8 * (ln >> 4) + i;
        int col  = n * 16 + (ln & 15);
        Ws[t] = f2bf(W[k * NDIM + col]);
    }
    __syncthreads();

    int wave = tx >> 6, lane = tx & 63;
    int g = lane >> 4;
    int rloc = wave * 16 + (lane & 15);

    f32x4 acc[8];
#pragma unroll
    for (int n = 0; n < 8; ++n) acc[n] = (f32x4){0.f, 0.f, 0.f, 0.f};

#pragma unroll
    for (int s = 0; s < 4; ++s) {
        int abyte = (rloc * 256 + s * 64 + g * 16) ^ ((rloc & 7) << 4);
        bf16x8 af = *(const bf16x8*)((const char*)Asm + abyte);
#pragma unroll
        for (int n = 0; n < 8; ++n) {
            bf16x8 bfr = *(const bf16x8*)(Ws + (((n * 4 + s) * 64 + lane) << 3));
            acc[n] = __builtin_amdgcn_mfma_f32_16x16x32_bf16(af, bfr, acc[n], 0, 0, 0);
        }
    }

    int colL = lane & 15;
    int rowbase = r0 + wave * 16 + g * 4;
#pragma unroll
    for (int n = 0; n < 8; ++n) {
#pragma unroll
        for (int r = 0; r < 4; ++r) {
            int row = rowbase + r;
            if (row < M)
                trans[(size_t)row * NDIM + n * 16 + colL] = f2bf(acc[n][r]);
        }
    }
}

// ---------------- k2: pure gather + segment-sum + epilogue ----------------
// 4 dst segments per wave (one per 16-lane slot), 8-deep clamped load pipeline.
// out[d] = (sum trans[src]) * rsqrt(clamp(ideg,1,K)) + bias
__global__ __launch_bounds__(256) void k2_gather(
        const uint16_t* __restrict__ trans,
        const int* __restrict__ ssrc, const int* __restrict__ row_start,
        const float* __restrict__ bias, const int* __restrict__ ideg,
        float* __restrict__ out, int ndst) {
    constexpr int U = 8;
    int gtid = blockIdx.x * blockDim.x + threadIdx.x;
    int wave = gtid >> 6;
    int lane = threadIdx.x & 63;
    int sub  = lane >> 4;          // dst slot 0..3
    int li   = lane & 15;          // 16B chunk within row
    int nwaves = (gridDim.x * blockDim.x) >> 6;

    float4 b0 = ((const float4*)bias)[li * 2];
    float4 b1 = ((const float4*)bias)[li * 2 + 1];

    for (int d0 = wave * 4; d0 < ndst; d0 += nwaves * 4) {
        int d = d0 + sub;
        int valid = (d < ndst);
        int s = 0, e = 0;
        if (valid) { s = row_start[d]; e = row_start[d + 1]; }
        int elast = (e > s) ? (e - 1) : 0;

        f32x2 acc[4];
#pragma unroll
        for (int k = 0; k < 4; ++k) acc[k] = (f32x2){0.f, 0.f};

        int idxv[U];
#pragma unroll
        for (int u = 0; u < U; ++u) idxv[u] = ssrc[min(s + u, elast)];

        int pos = s;
        while (__any(pos < e)) {
            uint4 v[U];
#pragma unroll
            for (int u = 0; u < U; ++u)
                v[u] = *(const uint4*)(trans + (size_t)idxv[u] * NDIM + li * 8);

            int npos = pos + U;
#pragma unroll
            for (int u = 0; u < U; ++u) idxv[u] = ssrc[min(npos + u, elast)];

#pragma unroll
            for (int u = 0; u < U; ++u) {
                if (pos + u < e) {
                    f32x2 t0 = {bf_lo(v[u].x), bf_hi(v[u].x)};
                    f32x2 t1 = {bf_lo(v[u].y), bf_hi(v[u].y)};
                    f32x2 t2 = {bf_lo(v[u].z), bf_hi(v[u].z)};
                    f32x2 t3 = {bf_lo(v[u].w), bf_hi(v[u].w)};
                    acc[0] += t0; acc[1] += t1; acc[2] += t2; acc[3] += t3;
                }
            }
            pos = npos;
        }

        if (valid) {
            float nrm = rsqrtf(fminf(fmaxf((float)ideg[d], 1.0f), KCLAMP));
            float4 o0, o1;
            o0.x = acc[0][0] * nrm + b0.x;
            o0.y = acc[0][1] * nrm + b0.y;
            o0.z = acc[1][0] * nrm + b0.z;
            o0.w = acc[1][1] * nrm + b0.w;
            o1.x = acc[2][0] * nrm + b1.x;
            o1.y = acc[2][1] * nrm + b1.y;
            o1.z = acc[3][0] * nrm + b1.z;
            o1.w = acc[3][1] * nrm + b1.w;
            ((float4*)out)[(size_t)d * (NDIM / 4) + li * 2]     = o0;
            ((float4*)out)[(size_t)d * (NDIM / 4) + li * 2 + 1] = o1;
        }
    }
}

// ---------------- fallbacks (workspace too small) ----------------
__global__ void k_rowptr(const int* __restrict__ sdst, int E,
                         int* __restrict__ row_start, int ndst) {
    int d = blockIdx.x * blockDim.x + threadIdx.x;
    if (d > ndst) return;
    int lo = 0, hi = E;
    while (lo < hi) {
        int mid = (lo + hi) >> 1;
        if (sdst[mid] < d) lo = mid + 1; else hi = mid;
    }
    row_start[d] = lo;
}

__global__ void k_agg_f32(const float* __restrict__ h, const int* __restrict__ odeg,
                          const int* __restrict__ ssrc, const int* __restrict__ row_start,
                          float* __restrict__ agg, int ndst) {
    int gtid = blockIdx.x * blockDim.x + threadIdx.x;
    int wave = gtid >> 6;
    int lane = threadIdx.x & 63;
    int nwaves = (gridDim.x * blockDim.x) >> 6;
    for (int d = wave; d < ndst; d += nwaves) {
        int s = row_start[d], e = row_start[d + 1];
        float a0 = 0.f, a1 = 0.f;
        for (int i = s; i < e; i++) {
            int s0 = ssrc[i];
            float nrm = rsqrtf(fmaxf((float)odeg[s0], 1.0f));
            float2 v = ((const float2*)h)[(size_t)s0 * (NDIM / 2) + lane];
            a0 += v.x * nrm;
            a1 += v.y * nrm;
        }
        float2 o; o.x = a0; o.y = a1;
        ((float2*)agg)[(size_t)d * (NDIM / 2) + lane] = o;
    }
}

__global__ __launch_bounds__(256) void k_gemm_f32(float* __restrict__ io,
                                                  const float* __restrict__ W,
                                                  const float* __restrict__ bias,
                                                  const int* __restrict__ ideg, int M) {
    __shared__ float Wsf[NDIM][NDIM];
    int tx = threadIdx.x;
    {
        const float4* Wv = (const float4*)W;
        float4* Wsv = (float4*)&Wsf[0][0];
        for (int i = tx; i < NDIM * NDIM / 4; i += 256) Wsv[i] = Wv[i];
    }
    __syncthreads();
    int cg = tx & 31, rg = tx >> 5;
    int r0 = blockIdx.x * 64 + rg * 8, c0 = cg * 4;
    float acc[8][4];
#pragma unroll
    for (int r = 0; r < 8; ++r)
#pragma unroll
        for (int c = 0; c < 4; ++c) acc[r][c] = 0.f;
    for (int k4 = 0; k4 < NDIM / 4; ++k4) {
        float4 wk0 = *(const float4*)&Wsf[4 * k4 + 0][c0];
        float4 wk1 = *(const float4*)&Wsf[4 * k4 + 1][c0];
        float4 wk2 = *(const float4*)&Wsf[4 * k4 + 2][c0];
        float4 wk3 = *(const float4*)&Wsf[4 * k4 + 3][c0];
#pragma unroll
        for (int r = 0; r < 8; ++r) {
            int row = r0 + r;
            if (row < M) {
                float4 a = ((const float4*)io)[(size_t)row * (NDIM / 4) + k4];
                acc[r][0] += a.x * wk0.x + a.y * wk1.x + a.z * wk2.x + a.w * wk3.x;
                acc[r][1] += a.x * wk0.y + a.y * wk1.y + a.z * wk2.y + a.w * wk3.y;
                acc[r][2] += a.x * wk0.z + a.y * wk1.z + a.z * wk2.z + a.w * wk3.z;
                acc[r][3] += a.x * wk0.w + a.y * wk1.w + a.z * wk2.w + a.w * wk3.w;
            }
        }
    }
    __syncthreads();
    float4 b = *(const float4*)&bias[c0];
#pragma unroll
    for (int r = 0; r < 8; ++r) {
        int row = r0 + r;
        if (row < M) {
            float nrm = rsqrtf(fminf(fmaxf((float)ideg[row], 1.0f), KCLAMP));
            float4 o;
            o.x = acc[r][0] * nrm + b.x;
            o.y = acc[r][1] * nrm + b.y;
            o.z = acc[r][2] * nrm + b.z;
            o.w = acc[r][3] * nrm + b.w;
            ((float4*)io)[(size_t)row * (NDIM / 4) + cg] = o;
        }
    }
}

extern "C" void kernel_launch(void* const* d_in, const int* in_sizes, int n_in,
                              void* d_out, int out_size, void* d_ws, size_t ws_size,
                              hipStream_t stream) {
    const float* h_src  = (const float*)d_in[0];
    const float* weight = (const float*)d_in[1];
    const float* bias   = (const float*)d_in[2];
    const int*   ssrc   = (const int*)d_in[3];
    const int*   sdst   = (const int*)d_in[4];
    const int*   odeg   = (const int*)d_in[5];
    const int*   ideg   = (const int*)d_in[6];
    float* out = (float*)d_out;

    int E    = in_sizes[3];
    int nsrc = in_sizes[0] / NDIM;
    int ndst = out_size / NDIM;

    // ws layout: [0,1MB) row_start ; [1MB, ..) trans (bf16 nsrc x 128)
    int*      row_start = (int*)d_ws;
    uint16_t* trans = (uint16_t*)((char*)d_ws + ((size_t)1 << 20));
    size_t need = ((size_t)1 << 20) + (size_t)nsrc * NDIM * 2;

    if (ws_size >= need) {
        int gemmBlocks = (nsrc + 63) / 64;
        int rpBlocks   = (ndst + 1 + 255) / 256;
        k1_trans_rowptr<<<gemmBlocks + rpBlocks, 256, 0, stream>>>(
            h_src, odeg, weight, trans, nsrc,
            sdst, E, row_start, ndst, gemmBlocks);
        k2_gather<<<2048, 256, 0, stream>>>(trans, ssrc, row_start, bias, ideg, out, ndst);
    } else {
        k_rowptr<<<(ndst + 1 + 255) / 256, 256, 0, stream>>>(sdst, E, row_start, ndst);
        k_agg_f32<<<2048, 256, 0, stream>>>(h_src, odeg, ssrc, row_start, out, ndst);
        k_gemm_f32<<<(ndst + 63) / 64, 256, 0, stream>>>(out, weight, bias, ideg, ndst);
    }
}

// Round 7
// 74.102 us; speedup vs baseline: 1.2368x; 1.2368x over previous
//
#include <hip/hip_runtime.h>
#include <hip/hip_bf16.h>
#include <cstdint>

#define NDIM 128
#define KCLAMP 10.0f

using bf16x8 = __attribute__((ext_vector_type(8))) short;
using f32x4  = __attribute__((ext_vector_type(4))) float;
using f32x2  = __attribute__((ext_vector_type(2))) float;

__device__ __forceinline__ uint16_t f2bf(float f) {
    uint32_t u = __float_as_uint(f);
    uint32_t r = (u + 0x7fffu + ((u >> 16) & 1u)) >> 16;   // RNE
    return (uint16_t)r;
}
__device__ __forceinline__ float bf_lo(uint32_t v) { return __uint_as_float(v << 16); }
__device__ __forceinline__ float bf_hi(uint32_t v) { return __uint_as_float(v & 0xffff0000u); }

// ---------------- prep: wfrag + rowptr in one launch ----------------
// wfrag[((n*4+s)*64+lane)*8+i] = bf16(W[k][col]), k=s*32+8*(lane>>4)+i, col=n*16+(lane&15)
__global__ void k_prep(const float* __restrict__ W, uint16_t* __restrict__ wfrag,
                       const int* __restrict__ sdst, int E,
                       int* __restrict__ row_start, int ndst, int wfBlocks) {
    int b = blockIdx.x;
    int tid = threadIdx.x;
    if (b < wfBlocks) {
        int t = b * 256 + tid;
        if (t >= NDIM * NDIM) return;
        int i    = t & 7;
        int lane = (t >> 3) & 63;
        int s    = (t >> 9) & 3;
        int n    = t >> 11;
        int k    = s * 32 + 8 * (lane >> 4) + i;
        int col  = n * 16 + (lane & 15);
        wfrag[t] = f2bf(W[k * NDIM + col]);
    } else {
        int d = (b - wfBlocks) * 256 + tid;     // lower_bound(sdst, d)
        if (d > ndst) return;
        int lo = 0, hi = E;
        while (lo < hi) {
            int mid = (lo + hi) >> 1;
            if (sdst[mid] < d) lo = mid + 1; else hi = mid;
        }
        row_start[d] = lo;
    }
}

// ---------------- k1: trans = bf16((h * norm_src) @ W) ----------------
// 256 thr = 4 waves, 64 rows/block. W frags from precomputed wfrag (coalesced
// int4 copy -> 32KB LDS). A-fragments loaded directly from global f32 h
// (two float4 per k-slice; wave covers 16 consecutive rows -> L1-coalesced),
// scaled by out-degree norm, converted to bf16 in-register.
__global__ __launch_bounds__(256) void k1_gemm(
        const float* __restrict__ h, const int* __restrict__ odeg,
        const uint16_t* __restrict__ wfrag, uint16_t* __restrict__ trans, int M) {
    __shared__ uint16_t Ws[NDIM * NDIM];     // 32 KB, B-frag layout
    int tx = threadIdx.x;
    for (int i = tx; i < NDIM * NDIM / 8; i += 256)
        ((int4*)Ws)[i] = ((const int4*)wfrag)[i];
    __syncthreads();

    int wave = tx >> 6, lane = tx & 63;
    int g = lane >> 4;
    int r0 = blockIdx.x * 64 + wave * 16;
    int arow = r0 + (lane & 15);
    if (arow >= M) arow = M - 1;             // clamp loads; stores predicated
    float nrm = rsqrtf(fmaxf((float)odeg[arow], 1.0f));
    const float4* Arow = (const float4*)(h + (size_t)arow * NDIM);

    f32x4 acc[8];
#pragma unroll
    for (int n = 0; n < 8; ++n) acc[n] = (f32x4){0.f, 0.f, 0.f, 0.f};

#pragma unroll
    for (int s = 0; s < 4; ++s) {
        float4 a0 = Arow[s * 8 + g * 2];     // k = s*32+g*8 .. +3
        float4 a1 = Arow[s * 8 + g * 2 + 1]; // k = s*32+g*8+4 .. +7
        bf16x8 af;
        af[0] = (short)f2bf(a0.x * nrm);
        af[1] = (short)f2bf(a0.y * nrm);
        af[2] = (short)f2bf(a0.z * nrm);
        af[3] = (short)f2bf(a0.w * nrm);
        af[4] = (short)f2bf(a1.x * nrm);
        af[5] = (short)f2bf(a1.y * nrm);
        af[6] = (short)f2bf(a1.z * nrm);
        af[7] = (short)f2bf(a1.w * nrm);
#pragma unroll
        for (int n = 0; n < 8; ++n) {
            bf16x8 bfr = *(const bf16x8*)(Ws + (((n * 4 + s) * 64 + lane) << 3));
            acc[n] = __builtin_amdgcn_mfma_f32_16x16x32_bf16(af, bfr, acc[n], 0, 0, 0);
        }
    }

    int colL = lane & 15;
    int rowbase = r0 + g * 4;
#pragma unroll
    for (int n = 0; n < 8; ++n) {
#pragma unroll
        for (int r = 0; r < 4; ++r) {
            int row = rowbase + r;
            if (row < M)
                trans[(size_t)row * NDIM + n * 16 + colL] = f2bf(acc[n][r]);
        }
    }
}

// ---------------- k2: pure gather + segment-sum + epilogue ----------------
// 4 dst segments per wave (one per 16-lane slot), 8-deep clamped load pipeline.
// out[d] = (sum trans[src]) * rsqrt(clamp(ideg,1,K)) + bias
__global__ __launch_bounds__(256) void k2_gather(
        const uint16_t* __restrict__ trans,
        const int* __restrict__ ssrc, const int* __restrict__ row_start,
        const float* __restrict__ bias, const int* __restrict__ ideg,
        float* __restrict__ out, int ndst) {
    constexpr int U = 8;
    int gtid = blockIdx.x * blockDim.x + threadIdx.x;
    int wave = gtid >> 6;
    int lane = threadIdx.x & 63;
    int sub  = lane >> 4;          // dst slot 0..3
    int li   = lane & 15;          // 16B chunk within row
    int nwaves = (gridDim.x * blockDim.x) >> 6;

    float4 b0 = ((const float4*)bias)[li * 2];
    float4 b1 = ((const float4*)bias)[li * 2 + 1];

    for (int d0 = wave * 4; d0 < ndst; d0 += nwaves * 4) {
        int d = d0 + sub;
        int valid = (d < ndst);
        int s = 0, e = 0;
        if (valid) { s = row_start[d]; e = row_start[d + 1]; }
        int elast = (e > s) ? (e - 1) : 0;

        f32x2 acc[4];
#pragma unroll
        for (int k = 0; k < 4; ++k) acc[k] = (f32x2){0.f, 0.f};

        int idxv[U];
#pragma unroll
        for (int u = 0; u < U; ++u) idxv[u] = ssrc[min(s + u, elast)];

        int pos = s;
        while (__any(pos < e)) {
            uint4 v[U];
#pragma unroll
            for (int u = 0; u < U; ++u)
                v[u] = *(const uint4*)(trans + (size_t)idxv[u] * NDIM + li * 8);

            int npos = pos + U;
#pragma unroll
            for (int u = 0; u < U; ++u) idxv[u] = ssrc[min(npos + u, elast)];

#pragma unroll
            for (int u = 0; u < U; ++u) {
                if (pos + u < e) {
                    f32x2 t0 = {bf_lo(v[u].x), bf_hi(v[u].x)};
                    f32x2 t1 = {bf_lo(v[u].y), bf_hi(v[u].y)};
                    f32x2 t2 = {bf_lo(v[u].z), bf_hi(v[u].z)};
                    f32x2 t3 = {bf_lo(v[u].w), bf_hi(v[u].w)};
                    acc[0] += t0; acc[1] += t1; acc[2] += t2; acc[3] += t3;
                }
            }
            pos = npos;
        }

        if (valid) {
            float nrm = rsqrtf(fminf(fmaxf((float)ideg[d], 1.0f), KCLAMP));
            float4 o0, o1;
            o0.x = acc[0][0] * nrm + b0.x;
            o0.y = acc[0][1] * nrm + b0.y;
            o0.z = acc[1][0] * nrm + b0.z;
            o0.w = acc[1][1] * nrm + b0.w;
            o1.x = acc[2][0] * nrm + b1.x;
            o1.y = acc[2][1] * nrm + b1.y;
            o1.z = acc[3][0] * nrm + b1.z;
            o1.w = acc[3][1] * nrm + b1.w;
            ((float4*)out)[(size_t)d * (NDIM / 4) + li * 2]     = o0;
            ((float4*)out)[(size_t)d * (NDIM / 4) + li * 2 + 1] = o1;
        }
    }
}

// ---------------- fallbacks (workspace too small) ----------------
__global__ void k_rowptr(const int* __restrict__ sdst, int E,
                         int* __restrict__ row_start, int ndst) {
    int d = blockIdx.x * blockDim.x + threadIdx.x;
    if (d > ndst) return;
    int lo = 0, hi = E;
    while (lo < hi) {
        int mid = (lo + hi) >> 1;
        if (sdst[mid] < d) lo = mid + 1; else hi = mid;
    }
    row_start[d] = lo;
}

__global__ void k_agg_f32(const float* __restrict__ h, const int* __restrict__ odeg,
                          const int* __restrict__ ssrc, const int* __restrict__ row_start,
                          float* __restrict__ agg, int ndst) {
    int gtid = blockIdx.x * blockDim.x + threadIdx.x;
    int wave = gtid >> 6;
    int lane = threadIdx.x & 63;
    int nwaves = (gridDim.x * blockDim.x) >> 6;
    for (int d = wave; d < ndst; d += nwaves) {
        int s = row_start[d], e = row_start[d + 1];
        float a0 = 0.f, a1 = 0.f;
        for (int i = s; i < e; i++) {
            int s0 = ssrc[i];
            float nrm = rsqrtf(fmaxf((float)odeg[s0], 1.0f));
            float2 v = ((const float2*)h)[(size_t)s0 * (NDIM / 2) + lane];
            a0 += v.x * nrm;
            a1 += v.y * nrm;
        }
        float2 o; o.x = a0; o.y = a1;
        ((float2*)agg)[(size_t)d * (NDIM / 2) + lane] = o;
    }
}

__global__ __launch_bounds__(256) void k_gemm_f32(float* __restrict__ io,
                                                  const float* __restrict__ W,
                                                  const float* __restrict__ bias,
                                                  const int* __restrict__ ideg, int M) {
    __shared__ float Wsf[NDIM][NDIM];
    int tx = threadIdx.x;
    {
        const float4* Wv = (const float4*)W;
        float4* Wsv = (float4*)&Wsf[0][0];
        for (int i = tx; i < NDIM * NDIM / 4; i += 256) Wsv[i] = Wv[i];
    }
    __syncthreads();
    int cg = tx & 31, rg = tx >> 5;
    int r0 = blockIdx.x * 64 + rg * 8, c0 = cg * 4;
    float acc[8][4];
#pragma unroll
    for (int r = 0; r < 8; ++r)
#pragma unroll
        for (int c = 0; c < 4; ++c) acc[r][c] = 0.f;
    for (int k4 = 0; k4 < NDIM / 4; ++k4) {
        float4 wk0 = *(const float4*)&Wsf[4 * k4 + 0][c0];
        float4 wk1 = *(const float4*)&Wsf[4 * k4 + 1][c0];
        float4 wk2 = *(const float4*)&Wsf[4 * k4 + 2][c0];
        float4 wk3 = *(const float4*)&Wsf[4 * k4 + 3][c0];
#pragma unroll
        for (int r = 0; r < 8; ++r) {
            int row = r0 + r;
            if (row < M) {
                float4 a = ((const float4*)io)[(size_t)row * (NDIM / 4) + k4];
                acc[r][0] += a.x * wk0.x + a.y * wk1.x + a.z * wk2.x + a.w * wk3.x;
                acc[r][1] += a.x * wk0.y + a.y * wk1.y + a.z * wk2.y + a.w * wk3.y;
                acc[r][2] += a.x * wk0.z + a.y * wk1.z + a.z * wk2.z + a.w * wk3.z;
                acc[r][3] += a.x * wk0.w + a.y * wk1.w + a.z * wk2.w + a.w * wk3.w;
            }
        }
    }
    __syncthreads();
    float4 b = *(const float4*)&bias[c0];
#pragma unroll
    for (int r = 0; r < 8; ++r) {
        int row = r0 + r;
        if (row < M) {
            float nrm = rsqrtf(fminf(fmaxf((float)ideg[row], 1.0f), KCLAMP));
            float4 o;
            o.x = acc[r][0] * nrm + b.x;
            o.y = acc[r][1] * nrm + b.y;
            o.z = acc[r][2] * nrm + b.z;
            o.w = acc[r][3] * nrm + b.w;
            ((float4*)io)[(size_t)row * (NDIM / 4) + cg] = o;
        }
    }
}

extern "C" void kernel_launch(void* const* d_in, const int* in_sizes, int n_in,
                              void* d_out, int out_size, void* d_ws, size_t ws_size,
                              hipStream_t stream) {
    const float* h_src  = (const float*)d_in[0];
    const float* weight = (const float*)d_in[1];
    const float* bias   = (const float*)d_in[2];
    const int*   ssrc   = (const int*)d_in[3];
    const int*   sdst   = (const int*)d_in[4];
    const int*   odeg   = (const int*)d_in[5];
    const int*   ideg   = (const int*)d_in[6];
    float* out = (float*)d_out;

    int E    = in_sizes[3];
    int nsrc = in_sizes[0] / NDIM;
    int ndst = out_size / NDIM;

    // ws layout: [0,1MB) row_start ; [1MB,1MB+32KB) wfrag ; [2MB, ..) trans
    int*      row_start = (int*)d_ws;
    uint16_t* wfrag = (uint16_t*)((char*)d_ws + ((size_t)1 << 20));
    uint16_t* trans = (uint16_t*)((char*)d_ws + ((size_t)2 << 20));
    size_t need = ((size_t)2 << 20) + (size_t)nsrc * NDIM * 2;

    if (ws_size >= need) {
        int wfBlocks = (NDIM * NDIM + 255) / 256;
        int rpBlocks = (ndst + 1 + 255) / 256;
        k_prep<<<wfBlocks + rpBlocks, 256, 0, stream>>>(
            weight, wfrag, sdst, E, row_start, ndst, wfBlocks);
        k1_gemm<<<(nsrc + 63) / 64, 256, 0, stream>>>(h_src, odeg, wfrag, trans, nsrc);
        k2_gather<<<2048, 256, 0, stream>>>(trans, ssrc, row_start, bias, ideg, out, ndst);
    } else {
        k_rowptr<<<(ndst + 1 + 255) / 256, 256, 0, stream>>>(sdst, E, row_start, ndst);
        k_agg_f32<<<2048, 256, 0, stream>>>(h_src, odeg, ssrc, row_start, out, ndst);
        k_gemm_f32<<<(ndst + 63) / 64, 256, 0, stream>>>(out, weight, bias, ideg, ndst);
    }
}